// Round 1
// baseline (531.734 us; speedup 1.0000x reference)
//
#include <hip/hip_runtime.h>
#include <hip/hip_bf16.h>

#define BB 16
#define NN 1024
#define DD 256
#define FF_ 128
#define LL 2
#define RR 2
#define DF 384
#define MM (BB*NN)

typedef __attribute__((ext_vector_type(8))) short s16x8;
typedef __attribute__((ext_vector_type(4))) float f32x4;

__device__ __forceinline__ unsigned short f2bf(float f){
  unsigned u = __builtin_bit_cast(unsigned, f);
  u += 0x7fff + ((u >> 16) & 1);
  return (unsigned short)(u >> 16);
}

__device__ __forceinline__ void gload16(const void* g, void* l){
  __builtin_amdgcn_global_load_lds(
      (const __attribute__((address_space(1))) unsigned int*)g,
      (__attribute__((address_space(3))) unsigned int*)l, 16, 0, 0);
}

#define MFMA16(a,b,c) __builtin_amdgcn_mfma_f32_16x16x32_bf16((a),(b),(c),0,0,0)

// ---------------- adj -> bitmask (R,B,N, 16 x u64) ----------------
__global__ __launch_bounds__(256) void pack_adj(const int* __restrict__ adj,
                                                unsigned long long* __restrict__ bits){
  int w = threadIdx.x >> 6, lane = threadIdx.x & 63;
  size_t row = (size_t)blockIdx.x * 4 + w;
  const int* a = adj + row * NN;
  unsigned long long* brow = bits + row * 16;
  #pragma unroll
  for (int j = 0; j < 16; ++j){
    unsigned long long m = __ballot(a[j*64 + lane] != 0);
    if (lane == 0) brow[j] = m;
  }
}

// ---------------- x1 = input_x @ WQi + b  (B,F) f32 ----------------
__global__ void x1_proj(const float* __restrict__ x, const float* __restrict__ wq,
                        const float* __restrict__ bq, float* __restrict__ x1){
  int b = blockIdx.x, j = threadIdx.x;
  float s = bq[j];
  for (int i = 0; i < FF_; ++i) s += x[b*FF_ + i] * wq[i*FF_ + j];
  x1[b*FF_ + j] = s;
}

// ------------- weight (K x 256) f32 -> (256 x K) bf16 transposed -------------
__global__ void w_to_bf16T(const float* __restrict__ in, unsigned short* __restrict__ out, int K){
  int o = blockIdx.x * 256 + threadIdx.x;   // o < 256*K
  int n = o / K, k = o - n*K;
  out[o] = f2bf(in[(size_t)k * 256 + n]);
}

// ------------- qc = concat(h, x1) -> bf16 (M x 384) -------------
__global__ void build_qc(const float* __restrict__ h, const float* __restrict__ x1,
                         unsigned short* __restrict__ qc){
  int m = blockIdx.y;
  int c = blockIdx.x * 128 + threadIdx.x;
  float v = (c < DD) ? h[(size_t)m * DD + c] : x1[(m >> 10) * FF_ + (c - DD)];
  qc[(size_t)m * DF + c] = f2bf(v);
}

// ------------- m97-style 128x128 GEMM, BK=32, Nout=256 fixed -------------
// C[m][n] = sum_k A[m][k] * Wt[n][k] + bias[n]
template<int OUTF32>
__global__ __launch_bounds__(256) void gemm128(const unsigned short* __restrict__ A,
    const unsigned short* __restrict__ Wt, const float* __restrict__ bias,
    void* __restrict__ out, int K, int nk){
  __shared__ unsigned short As[128*32];
  __shared__ unsigned short Bs[128*32];
  int t = threadIdx.x, lane = t & 63, w = t >> 6;
  int wr = w >> 1, wc = w & 1, l15 = lane & 15, lhi = lane >> 4;
  int bm = blockIdx.x, bn = blockIdx.y;
  f32x4 acc[4][4];
  #pragma unroll
  for (int m = 0; m < 4; ++m)
    #pragma unroll
    for (int n = 0; n < 4; ++n) acc[m][n] = (f32x4){0.f,0.f,0.f,0.f};

  for (int kk = 0; kk < nk; ++kk){
    __syncthreads();
    #pragma unroll
    for (int i = 0; i < 2; ++i){
      int off = w*2048 + i*1024 + lane*16;
      int row = off >> 6, cb = off & 63;
      gload16((const char*)(A  + ((size_t)(bm*128 + row)*K + kk*32)) + cb,
              (char*)As + (w*2048 + i*1024));
      gload16((const char*)(Wt + ((size_t)(bn*128 + row)*K + kk*32)) + cb,
              (char*)Bs + (w*2048 + i*1024));
    }
    __syncthreads();
    s16x8 af[4], bfr[4];
    #pragma unroll
    for (int m = 0; m < 4; ++m) af[m]  = *(const s16x8*)&As[(wr*64 + m*16 + l15)*32 + lhi*8];
    #pragma unroll
    for (int n = 0; n < 4; ++n) bfr[n] = *(const s16x8*)&Bs[(wc*64 + n*16 + l15)*32 + lhi*8];
    #pragma unroll
    for (int m = 0; m < 4; ++m)
      #pragma unroll
      for (int n = 0; n < 4; ++n)
        acc[m][n] = MFMA16(af[m], bfr[n], acc[m][n]);
  }

  #pragma unroll
  for (int n = 0; n < 4; ++n){
    int gn = bn*128 + wc*64 + n*16 + l15;
    float bv = bias[gn];
    #pragma unroll
    for (int m = 0; m < 4; ++m){
      int gm = bm*128 + wr*64 + m*16 + lhi*4;
      #pragma unroll
      for (int i = 0; i < 4; ++i){
        float v = acc[m][n][i] + bv;
        size_t o = (size_t)(gm + i) * DD + gn;
        if (OUTF32) ((float*)out)[o] = v;
        else        ((unsigned short*)out)[o] = f2bf(v);
      }
    }
  }
}

// ------------- V (b: 1024x256) -> VT (b: 256x1024), bf16 -------------
__global__ __launch_bounds__(256) void transpose_v(const unsigned short* __restrict__ v,
                                                   unsigned short* __restrict__ vt){
  __shared__ unsigned short tl[64][66];
  int b = blockIdx.z, n0 = blockIdx.x*64, d0 = blockIdx.y*64;
  int t = threadIdx.x;
  #pragma unroll
  for (int it = 0; it < 16; ++it){
    int idx = t + it*256;
    int rr = idx >> 6, cc = idx & 63;
    tl[rr][cc] = v[((size_t)(b*NN + n0 + rr))*DD + d0 + cc];
  }
  __syncthreads();
  #pragma unroll
  for (int it = 0; it < 16; ++it){
    int idx = t + it*256;
    int rr = idx >> 6, cc = idx & 63;
    vt[((size_t)(b*DD + d0 + rr))*NN + n0 + cc] = tl[cc][rr];
  }
}

// ------------- flash attention with adj mask -------------
// grid (16 qtiles, B, R), block 256 (4 waves, 16 q-rows each)
__global__ __launch_bounds__(256) void attn(const unsigned short* __restrict__ Qb,
    const unsigned short* __restrict__ K0, const unsigned short* __restrict__ K1,
    const unsigned short* __restrict__ VT0, const unsigned short* __restrict__ VT1,
    const unsigned long long* __restrict__ bits, unsigned short* __restrict__ hc){
  __shared__ unsigned short Kt[64*256];   // 32 KB, XOR-swizzled rows (512 B)
  __shared__ unsigned short Vt[256*64];   // 32 KB, XOR-swizzled rows (128 B)
  __shared__ unsigned short Pl[4][16*72]; // per-wave P tile, padded rows
  int t = threadIdx.x, lane = t & 63, w = t >> 6, l15 = lane & 15, lhi = lane >> 4;
  int qt = blockIdx.x, b = blockIdx.y, r = blockIdx.z;
  const unsigned short* Kb = r ? K1 : K0;
  const unsigned short* Vb = r ? VT1 : VT0;
  const float scale = 0.0625f;

  // Q fragments in registers: 8 x (16x32) A-frags
  s16x8 qf[8];
  {
    int qrow = qt*64 + w*16 + l15;
    const unsigned short* qp = Qb + ((size_t)(b*NN + qrow))*DD + lhi*8;
    #pragma unroll
    for (int dc = 0; dc < 8; ++dc) qf[dc] = *(const s16x8*)(qp + dc*32);
  }

  f32x4 acc[16];
  #pragma unroll
  for (int i = 0; i < 16; ++i) acc[i] = (f32x4){0.f,0.f,0.f,0.f};
  float mrow[4] = {-1e30f,-1e30f,-1e30f,-1e30f};
  float lrow[4] = {0.f,0.f,0.f,0.f};
  size_t bitrow = ((size_t)(r*BB + b))*NN + qt*64 + w*16 + lhi*4;

  for (int kt = 0; kt < 16; ++kt){
    __syncthreads();
    // stage K-tile (64 x 256), swizzled: LDS[row][c] = G[row][c ^ ((row&7)<<4)]
    #pragma unroll
    for (int i = 0; i < 8; ++i){
      int off = w*8192 + i*1024 + lane*16;
      int row = off >> 9, cb = off & 511;
      int scb = cb ^ ((row & 7) << 4);
      gload16((const char*)(Kb + ((size_t)(b*NN + kt*64 + row))*DD) + scb,
              (char*)Kt + (w*8192 + i*1024));
    }
    // stage VT-tile (256 x 64), swizzled
    #pragma unroll
    for (int i = 0; i < 8; ++i){
      int off = w*8192 + i*1024 + lane*16;
      int row = off >> 7, cb = off & 127;
      int scb = cb ^ ((row & 7) << 4);
      gload16((const char*)(Vb + ((size_t)(b*DD + row))*NN + kt*64) + scb,
              (char*)Vt + (w*8192 + i*1024));
    }
    __syncthreads();

    // S = Q K^T  (4 frags of 16q x 16k, over D=256)
    f32x4 sf[4];
    #pragma unroll
    for (int ks = 0; ks < 4; ++ks){
      sf[ks] = (f32x4){0.f,0.f,0.f,0.f};
      int krow = ks*16 + l15;
      #pragma unroll
      for (int dc = 0; dc < 8; ++dc){
        int bo = krow*512 + (((dc*32 + lhi*8)*2) ^ ((krow & 7) << 4));
        s16x8 kf = *(const s16x8*)((const char*)Kt + bo);
        sf[ks] = MFMA16(qf[dc], kf, sf[ks]);
      }
    }

    // mask + online softmax
    unsigned long long mw[4];
    #pragma unroll
    for (int i = 0; i < 4; ++i) mw[i] = bits[(bitrow + i)*16 + kt];
    float p[4][4];
    #pragma unroll
    for (int i = 0; i < 4; ++i){
      float tm = -1e30f;
      #pragma unroll
      for (int ks = 0; ks < 4; ++ks){
        float s = sf[ks][i] * scale;
        bool on = (mw[i] >> (ks*16 + l15)) & 1ULL;
        s = on ? s : -1e9f;
        p[ks][i] = s;
        tm = fmaxf(tm, s);
      }
      #pragma unroll
      for (int xm = 1; xm < 16; xm <<= 1) tm = fmaxf(tm, __shfl_xor(tm, xm));
      float mn = fmaxf(mrow[i], tm);
      float f = __expf(mrow[i] - mn);
      mrow[i] = mn;
      float rs = 0.f;
      #pragma unroll
      for (int ks = 0; ks < 4; ++ks){ float e = __expf(p[ks][i] - mn); p[ks][i] = e; rs += e; }
      #pragma unroll
      for (int xm = 1; xm < 16; xm <<= 1) rs += __shfl_xor(rs, xm);
      lrow[i] = lrow[i]*f + rs;
      #pragma unroll
      for (int dt = 0; dt < 16; ++dt) acc[dt][i] *= f;
    }

    // P -> bf16 -> per-wave LDS (padded rows: 72 ushorts)
    unsigned short* pw = &Pl[w][0];
    #pragma unroll
    for (int i = 0; i < 4; ++i)
      #pragma unroll
      for (int ks = 0; ks < 4; ++ks)
        pw[(lhi*4 + i)*72 + ks*16 + l15] = f2bf(p[ks][i]);

    s16x8 pa[2];
    #pragma unroll
    for (int kc = 0; kc < 2; ++kc)
      pa[kc] = *(const s16x8*)&pw[l15*72 + kc*32 + lhi*8];

    // PV: 16 d-tiles x 2 k-chunks
    #pragma unroll
    for (int dt = 0; dt < 16; ++dt){
      int vrow = dt*16 + l15;
      #pragma unroll
      for (int kc = 0; kc < 2; ++kc){
        int bo = vrow*128 + (((kc*32 + lhi*8)*2) ^ ((vrow & 7) << 4));
        s16x8 vf = *(const s16x8*)((const char*)Vt + bo);
        acc[dt] = MFMA16(pa[kc], vf, acc[dt]);
      }
    }
  }

  // epilogue: normalize and write to h_concat (B,N,512) bf16
  #pragma unroll
  for (int i = 0; i < 4; ++i){
    float inv = 1.f / lrow[i];
    int q = qt*64 + w*16 + lhi*4 + i;
    unsigned short* hrow = hc + ((size_t)(b*NN + q))*(RR*DD) + r*DD;
    #pragma unroll
    for (int dt = 0; dt < 16; ++dt)
      hrow[dt*16 + l15] = f2bf(acc[dt][i] * inv);
  }
}

// ------------- relu + residual + layernorm, 1 wave per row -------------
__global__ __launch_bounds__(256) void ln_res(const float* __restrict__ ff,
    const float* __restrict__ hin, const float* __restrict__ g,
    const float* __restrict__ bv, float* __restrict__ hout){
  int w = threadIdx.x >> 6, lane = threadIdx.x & 63;
  size_t row = (size_t)blockIdx.x * 4 + w;
  f32x4 fv = *(const f32x4*)(ff  + row*DD + lane*4);
  f32x4 hv = *(const f32x4*)(hin + row*DD + lane*4);
  float x[4], s = 0.f, ss = 0.f;
  #pragma unroll
  for (int j = 0; j < 4; ++j){ x[j] = fmaxf(fv[j], 0.f) + hv[j]; s += x[j]; ss += x[j]*x[j]; }
  #pragma unroll
  for (int xm = 1; xm < 64; xm <<= 1){ s += __shfl_xor(s, xm); ss += __shfl_xor(ss, xm); }
  float mu = s * (1.f/256.f);
  float var = ss * (1.f/256.f) - mu*mu;
  float rstd = rsqrtf(var + 1e-5f);
  f32x4 o;
  #pragma unroll
  for (int j = 0; j < 4; ++j){ int c = lane*4 + j; o[j] = (x[j]-mu)*rstd*g[c] + bv[c]; }
  *(f32x4*)(hout + row*DD + lane*4) = o;
}

extern "C" void kernel_launch(void* const* d_in, const int* in_sizes, int n_in,
                              void* d_out, int out_size, void* d_ws, size_t ws_size,
                              hipStream_t stream){
  (void)in_sizes; (void)n_in; (void)out_size; (void)ws_size;
  const float* node  = (const float*)d_in[0];
  const float* inx   = (const float*)d_in[1];
  const int*   adj   = (const int*)d_in[2];
  const float* WQi_w = (const float*)d_in[3];
  const float* WQi_b = (const float*)d_in[4];
  const float* WQ_w  = (const float*)d_in[5];
  const float* WQ_b  = (const float*)d_in[6];
  const float* WK_w  = (const float*)d_in[7];
  const float* WK_b  = (const float*)d_in[8];
  const float* WV_w  = (const float*)d_in[9];
  const float* WV_b  = (const float*)d_in[10];
  const float* WF_w  = (const float*)d_in[11];
  const float* WF_b  = (const float*)d_in[12];
  const float* ln_g  = (const float*)d_in[13];
  const float* ln_b  = (const float*)d_in[14];
  float* hout = (float*)d_out;

  char* wsp = (char*)d_ws;
  auto alloc = [&](size_t n){ char* p = wsp; wsp += (n + 255) & ~(size_t)255; return p; };
  unsigned long long* bits = (unsigned long long*)alloc((size_t)RR*BB*NN*16*8);
  unsigned short* qc   = (unsigned short*)alloc((size_t)MM*DF*2);
  float*          x1   = (float*)alloc((size_t)BB*FF_*4);
  unsigned short* wtq  = (unsigned short*)alloc((size_t)DD*DF*2);
  unsigned short* wtk0 = (unsigned short*)alloc((size_t)DD*DF*2);
  unsigned short* wtk1 = (unsigned short*)alloc((size_t)DD*DF*2);
  unsigned short* wtv0 = (unsigned short*)alloc((size_t)DD*DF*2);
  unsigned short* wtv1 = (unsigned short*)alloc((size_t)DD*DF*2);
  unsigned short* wtf  = (unsigned short*)alloc((size_t)DD*512*2);
  unsigned short* qb   = (unsigned short*)alloc((size_t)MM*DD*2);
  unsigned short* kb0  = (unsigned short*)alloc((size_t)MM*DD*2);
  unsigned short* kb1  = (unsigned short*)alloc((size_t)MM*DD*2);
  unsigned short* vb0  = (unsigned short*)alloc((size_t)MM*DD*2);
  unsigned short* vb1  = (unsigned short*)alloc((size_t)MM*DD*2);
  unsigned short* vt0  = (unsigned short*)alloc((size_t)MM*DD*2);
  unsigned short* vt1  = (unsigned short*)alloc((size_t)MM*DD*2);
  unsigned short* hc   = (unsigned short*)alloc((size_t)MM*512*2);
  float*          ffo  = (float*)alloc((size_t)MM*DD*4);

  pack_adj<<<RR*BB*NN/4, 256, 0, stream>>>(adj, bits);

  for (int l = 0; l < LL; ++l){
    x1_proj<<<BB, FF_, 0, stream>>>(inx, WQi_w + (size_t)l*FF_*FF_, WQi_b + l*FF_, x1);
    w_to_bf16T<<<DF,  256, 0, stream>>>(WQ_w + (size_t)l*DF*DD, wtq, DF);
    w_to_bf16T<<<DF,  256, 0, stream>>>(WK_w + (size_t)(l*RR+0)*DF*DD, wtk0, DF);
    w_to_bf16T<<<DF,  256, 0, stream>>>(WK_w + (size_t)(l*RR+1)*DF*DD, wtk1, DF);
    w_to_bf16T<<<DF,  256, 0, stream>>>(WV_w + (size_t)(l*RR+0)*DF*DD, wtv0, DF);
    w_to_bf16T<<<DF,  256, 0, stream>>>(WV_w + (size_t)(l*RR+1)*DF*DD, wtv1, DF);
    w_to_bf16T<<<512, 256, 0, stream>>>(WF_w + (size_t)l*512*DD, wtf, 512);

    const float* hsrc = l ? (const float*)hout : node;
    build_qc<<<dim3(3, MM), 128, 0, stream>>>(hsrc, x1, qc);

    gemm128<0><<<dim3(128,2), 256, 0, stream>>>(qc, wtq,  WQ_b + l*DD,          qb,  DF, DF/32);
    gemm128<0><<<dim3(128,2), 256, 0, stream>>>(qc, wtk0, WK_b + (l*RR+0)*DD,   kb0, DF, DF/32);
    gemm128<0><<<dim3(128,2), 256, 0, stream>>>(qc, wtk1, WK_b + (l*RR+1)*DD,   kb1, DF, DF/32);
    gemm128<0><<<dim3(128,2), 256, 0, stream>>>(qc, wtv0, WV_b + (l*RR+0)*DD,   vb0, DF, DF/32);
    gemm128<0><<<dim3(128,2), 256, 0, stream>>>(qc, wtv1, WV_b + (l*RR+1)*DD,   vb1, DF, DF/32);

    transpose_v<<<dim3(16,4,BB), 256, 0, stream>>>(vb0, vt0);
    transpose_v<<<dim3(16,4,BB), 256, 0, stream>>>(vb1, vt1);

    attn<<<dim3(16,BB,RR), 256, 0, stream>>>(qb, kb0, kb1, vt0, vt1, bits, hc);

    gemm128<1><<<dim3(128,2), 256, 0, stream>>>(hc, wtf, WF_b + l*DD, ffo, 512, 512/32);

    ln_res<<<MM/4, 256, 0, stream>>>(ffo, hsrc, ln_g + l*DD, ln_b + l*DD, hout);
  }
}

// Round 2
// 344.248 us; speedup vs baseline: 1.5446x; 1.5446x over previous
//
#include <hip/hip_runtime.h>
#include <hip/hip_bf16.h>

#define BB 16
#define NN 1024
#define DD 256
#define FF_ 128
#define LL 2
#define RR 2
#define DF 384
#define MM (BB*NN)
#define NPROJ 1280

typedef __attribute__((ext_vector_type(8))) short s16x8;
typedef __attribute__((ext_vector_type(4))) float f32x4;

__device__ __forceinline__ unsigned short f2bf(float f){
  unsigned u = __builtin_bit_cast(unsigned, f);
  u += 0x7fff + ((u >> 16) & 1);
  return (unsigned short)(u >> 16);
}

__device__ __forceinline__ void gload16(const void* g, void* l){
  __builtin_amdgcn_global_load_lds(
      (const __attribute__((address_space(1))) unsigned int*)g,
      (__attribute__((address_space(3))) unsigned int*)l, 16, 0, 0);
}

#define MFMA16(a,b,c) __builtin_amdgcn_mfma_f32_16x16x32_bf16((a),(b),(c),0,0,0)

// ---------------- adj -> bitmask (R,B,N, 16 x u64) ----------------
__global__ __launch_bounds__(256) void pack_adj(const int* __restrict__ adj,
                                                unsigned long long* __restrict__ bits){
  int w = threadIdx.x >> 6, lane = threadIdx.x & 63;
  size_t row = (size_t)blockIdx.x * 4 + w;
  const int* a = adj + row * NN;
  unsigned long long* brow = bits + row * 16;
  #pragma unroll
  for (int j = 0; j < 16; ++j){
    unsigned long long m = __ballot(a[j*64 + lane] != 0);
    if (lane == 0) brow[j] = m;
  }
}

// ---------------- x1 = input_x @ WQi + b  (B,F) f32 ----------------
__global__ void x1_proj(const float* __restrict__ x, const float* __restrict__ wq,
                        const float* __restrict__ bq, float* __restrict__ x1){
  int b = blockIdx.x, j = threadIdx.x;
  float s = bq[j];
  for (int i = 0; i < FF_; ++i) s += x[b*FF_ + i] * wq[i*FF_ + j];
  x1[b*FF_ + j] = s;
}

// ------------- weight (K x 256) f32 -> (256 x K) bf16 transposed -------------
__global__ void w_to_bf16T(const float* __restrict__ in, unsigned short* __restrict__ out, int K){
  int o = blockIdx.x * 256 + threadIdx.x;
  int n = o / K, k = o - n*K;
  out[o] = f2bf(in[(size_t)k * 256 + n]);
}

// ------------- concat Q/K0/K1/V0/V1 weights -> wtall[1280][384] bf16 -------------
__global__ void wcat(const float* __restrict__ WQ, const float* __restrict__ WK,
                     const float* __restrict__ WV, unsigned short* __restrict__ wt){
  int o = blockIdx.x * 256 + threadIdx.x;   // < 1280*384
  int n = o / DF, k = o - n*DF;
  float v;
  if (n < 256)      v = WQ[(size_t)k*256 + n];
  else if (n < 768) v = WK[(size_t)((n-256)>>8)*(DF*256) + (size_t)k*256 + ((n-256)&255)];
  else              v = WV[(size_t)((n-768)>>8)*(DF*256) + (size_t)k*256 + ((n-768)&255)];
  wt[o] = f2bf(v);
}

__global__ void bcat(const float* __restrict__ bq, const float* __restrict__ bk,
                     const float* __restrict__ bv, float* __restrict__ ball){
  int n = blockIdx.x * 256 + threadIdx.x;
  if (n >= NPROJ) return;
  ball[n] = (n < 256) ? bq[n] : (n < 768) ? bk[n-256] : bv[n-768];
}

// ------------- qc h-part from f32 source (layer 0) -------------
__global__ __launch_bounds__(256) void qc_h(const float* __restrict__ h, unsigned short* __restrict__ qc){
  int o = blockIdx.x * 256 + threadIdx.x;   // < MM*256
  int m = o >> 8, c = o & 255;
  qc[(size_t)m * DF + c] = f2bf(h[o]);
}

// ------------- qc x1-part (per layer) -------------
__global__ __launch_bounds__(256) void qc_x1(const float* __restrict__ x1, unsigned short* __restrict__ qc){
  int m = blockIdx.x * 2 + (threadIdx.x >> 7);
  int c = threadIdx.x & 127;
  qc[(size_t)m * DF + 256 + c] = f2bf(x1[(m >> 10) * FF_ + c]);
}

// ------------- 2-phase prefetch 128x128 GEMM, BK=32 -------------
// C[m][gn] = sum_k A[m][k] * Wt[gn][k] + bias[gn]; out row stride ldo
template<int OUTF32>
__global__ __launch_bounds__(256) void gemm2(const unsigned short* __restrict__ A, int lda,
    const unsigned short* __restrict__ Wt, const float* __restrict__ bias,
    void* __restrict__ out, int ldo, int nk){
  __shared__ unsigned short As[2][128*32];
  __shared__ unsigned short Bs[2][128*32];
  int t = threadIdx.x, lane = t & 63, w = t >> 6;
  int wr = w >> 1, wc = w & 1, l15 = lane & 15, lhi = lane >> 4;
  int bm = blockIdx.x, bn = blockIdx.y;
  f32x4 acc[4][4];
  #pragma unroll
  for (int m = 0; m < 4; ++m)
    #pragma unroll
    for (int n = 0; n < 4; ++n) acc[m][n] = (f32x4){0.f,0.f,0.f,0.f};

  auto STAGE = [&](int bufi, int kk){
    #pragma unroll
    for (int i = 0; i < 2; ++i){
      int base = w*2048 + i*1024;
      int off = base + lane*16;
      int row = off >> 6, cb = off & 63;
      gload16((const char*)A  + ((size_t)(bm*128 + row)*lda + kk*32)*2 + cb,
              (char*)As[bufi] + base);
      gload16((const char*)Wt + ((size_t)(bn*128 + row)*DF  + 0)*0 + ((size_t)(bn*128 + row)*lda + kk*32)*2 + cb,
              (char*)Bs[bufi] + base);
    }
  };

  STAGE(0, 0);
  __syncthreads();
  for (int kk = 0; kk < nk; ++kk){
    int cur = kk & 1;
    if (kk + 1 < nk) STAGE(cur ^ 1, kk + 1);
    s16x8 af[4], bfr[4];
    #pragma unroll
    for (int m = 0; m < 4; ++m) af[m]  = *(const s16x8*)&As[cur][(wr*64 + m*16 + l15)*32 + lhi*8];
    #pragma unroll
    for (int n = 0; n < 4; ++n) bfr[n] = *(const s16x8*)&Bs[cur][(wc*64 + n*16 + l15)*32 + lhi*8];
    #pragma unroll
    for (int m = 0; m < 4; ++m)
      #pragma unroll
      for (int n = 0; n < 4; ++n)
        acc[m][n] = MFMA16(af[m], bfr[n], acc[m][n]);
    __syncthreads();
  }

  #pragma unroll
  for (int n = 0; n < 4; ++n){
    int gn = bn*128 + wc*64 + n*16 + l15;
    float bv = bias[gn];
    #pragma unroll
    for (int m = 0; m < 4; ++m){
      int gm = bm*128 + wr*64 + m*16 + lhi*4;
      #pragma unroll
      for (int i = 0; i < 4; ++i){
        float v = acc[m][n][i] + bv;
        size_t o = (size_t)(gm + i) * ldo + gn;
        if (OUTF32) ((float*)out)[o] = v;
        else        ((unsigned short*)out)[o] = f2bf(v);
      }
    }
  }
}

// ------------- V slices of POUT -> VT (r,b: 256x1024), bf16 -------------
__global__ __launch_bounds__(256) void transpose2(const unsigned short* __restrict__ P,
                                                  unsigned short* __restrict__ vt){
  __shared__ unsigned short tl[64][66];
  int z = blockIdx.z;               // r*16+b
  int b = z & 15, r = z >> 4;
  int n0 = blockIdx.x*64, d0 = blockIdx.y*64;
  int t = threadIdx.x;
  #pragma unroll
  for (int it = 0; it < 16; ++it){
    int idx = t + it*256;
    int rr = idx >> 6, cc = idx & 63;
    tl[rr][cc] = P[(size_t)(b*NN + n0 + rr)*NPROJ + 768 + r*256 + d0 + cc];
  }
  __syncthreads();
  #pragma unroll
  for (int it = 0; it < 16; ++it){
    int idx = t + it*256;
    int rr = idx >> 6, cc = idx & 63;
    vt[((size_t)z*256 + d0 + rr)*NN + n0 + cc] = tl[cc][rr];
  }
}

// ------------- flash attention, 8 waves / 128 q-rows per block -------------
// grid 256 (1D, XCD-swizzled), block 512
__global__ __launch_bounds__(512, 2) void attn2(const unsigned short* __restrict__ P,
    const unsigned short* __restrict__ VT, const unsigned long long* __restrict__ bits,
    unsigned short* __restrict__ hc){
  __shared__ unsigned short Kt[64*256];   // 32 KB, XOR-swizzled rows (512 B)
  __shared__ unsigned short Vt[256*64];   // 32 KB, XOR-swizzled rows (128 B)
  __shared__ unsigned short Pl[8][16*72]; // per-wave P tile, padded rows
  int t = threadIdx.x, lane = t & 63, w = t >> 6, l15 = lane & 15, lhi = lane >> 4;
  int F = blockIdx.x;
  int xcd = F & 7, j = F >> 3;            // j in 0..31
  int qt = j & 7;
  int gidx = xcd*4 + (j >> 3);            // 0..31
  int b = gidx & 15, r = gidx >> 4;
  const float scale = 0.0625f;

  const unsigned short* Qb = P;                       // row stride 1280, cols 0..255
  size_t kcol = 256 + (size_t)r*256;                  // K slice offset in POUT
  const unsigned short* Vb = VT + ((size_t)(r*16 + b))*256*NN;

  // Q fragments in registers
  s16x8 qf[8];
  {
    int qrow = qt*128 + w*16 + l15;
    const unsigned short* qp = Qb + ((size_t)(b*NN + qrow))*NPROJ + lhi*8;
    #pragma unroll
    for (int dc = 0; dc < 8; ++dc) qf[dc] = *(const s16x8*)(qp + dc*32);
  }

  f32x4 acc[16];
  #pragma unroll
  for (int i = 0; i < 16; ++i) acc[i] = (f32x4){0.f,0.f,0.f,0.f};
  float mrow[4] = {-1e30f,-1e30f,-1e30f,-1e30f};
  float lrow[4] = {0.f,0.f,0.f,0.f};
  size_t bitrow = ((size_t)(r*BB + b))*NN + qt*128 + w*16 + lhi*4;

  for (int kt = 0; kt < 16; ++kt){
    __syncthreads();
    // stage K-tile (64 x 256): 4 loads/thread, swizzled source
    #pragma unroll
    for (int i = 0; i < 4; ++i){
      int base = w*4096 + i*512;
      int off = base + lane*16;           // covers w*4096 .. w*4096+4095 over i? no:
      (void)off;
    }
    // (corrected staging below: 4 chunks of 1024B per wave half -> use i<4 with 1024 stride over 8 waves)
    #pragma unroll
    for (int i = 0; i < 4; ++i){
      int base = w*4096 + i*1024;
      int off = base + lane*16;           // [0, 32768)
      int row = off >> 9, cb = off & 511;
      int scb = cb ^ ((row & 7) << 4);
      gload16((const char*)P + ((size_t)(b*NN + kt*64 + row)*NPROJ + kcol)*2 + scb,
              (char*)Kt + base);
    }
    // stage VT-tile (256 x 64), swizzled
    #pragma unroll
    for (int i = 0; i < 4; ++i){
      int base = w*4096 + i*1024;
      int off = base + lane*16;
      int row = off >> 7, cb = off & 127;
      int scb = cb ^ ((row & 7) << 4);
      gload16((const char*)Vb + ((size_t)row*NN + kt*64)*2 + scb,
              (char*)Vt + base);
    }
    __syncthreads();

    // S = Q K^T
    f32x4 sf[4];
    #pragma unroll
    for (int ks = 0; ks < 4; ++ks){
      sf[ks] = (f32x4){0.f,0.f,0.f,0.f};
      int krow = ks*16 + l15;
      #pragma unroll
      for (int dc = 0; dc < 8; ++dc){
        int bo = krow*512 + (((dc*32 + lhi*8)*2) ^ ((krow & 7) << 4));
        s16x8 kf = *(const s16x8*)((const char*)Kt + bo);
        sf[ks] = MFMA16(qf[dc], kf, sf[ks]);
      }
    }

    // mask + online softmax (write P to LDS inside loop)
    unsigned short* pw = &Pl[w][0];
    #pragma unroll
    for (int i = 0; i < 4; ++i){
      unsigned long long mwv = bits[(bitrow + i)*16 + kt];
      float sv[4]; float tm = -1e30f;
      #pragma unroll
      for (int ks = 0; ks < 4; ++ks){
        float s = sf[ks][i] * scale;
        bool on = (mwv >> (ks*16 + l15)) & 1ULL;
        s = on ? s : -1e9f;
        sv[ks] = s;
        tm = fmaxf(tm, s);
      }
      #pragma unroll
      for (int xm = 1; xm < 16; xm <<= 1) tm = fmaxf(tm, __shfl_xor(tm, xm));
      float mn = fmaxf(mrow[i], tm);
      float f = __expf(mrow[i] - mn);
      mrow[i] = mn;
      float rs = 0.f;
      #pragma unroll
      for (int ks = 0; ks < 4; ++ks){
        float e = __expf(sv[ks] - mn);
        pw[(lhi*4 + i)*72 + ks*16 + l15] = f2bf(e);
        rs += e;
      }
      #pragma unroll
      for (int xm = 1; xm < 16; xm <<= 1) rs += __shfl_xor(rs, xm);
      lrow[i] = lrow[i]*f + rs;
      #pragma unroll
      for (int dt = 0; dt < 16; ++dt) acc[dt][i] *= f;
    }

    s16x8 pa[2];
    #pragma unroll
    for (int kc = 0; kc < 2; ++kc)
      pa[kc] = *(const s16x8*)&pw[l15*72 + kc*32 + lhi*8];

    // PV
    #pragma unroll
    for (int dt = 0; dt < 16; ++dt){
      int vrow = dt*16 + l15;
      #pragma unroll
      for (int kc = 0; kc < 2; ++kc){
        int bo = vrow*128 + (((kc*32 + lhi*8)*2) ^ ((vrow & 7) << 4));
        s16x8 vf = *(const s16x8*)((const char*)Vt + bo);
        acc[dt] = MFMA16(pa[kc], vf, acc[dt]);
      }
    }
  }

  // epilogue -> h_concat (B,N,512) bf16
  #pragma unroll
  for (int i = 0; i < 4; ++i){
    float inv = 1.f / lrow[i];
    int q = qt*128 + w*16 + lhi*4 + i;
    unsigned short* hrow = hc + ((size_t)(b*NN + q))*(RR*DD) + r*DD;
    #pragma unroll
    for (int dt = 0; dt < 16; ++dt)
      hrow[dt*16 + l15] = f2bf(acc[dt][i] * inv);
  }
}

// ------------- relu + residual + layernorm (+ optional qc write) -------------
template<int WRITEQC>
__global__ __launch_bounds__(256) void ln_res2(const float* __restrict__ ff,
    const float* __restrict__ hin, const float* __restrict__ g,
    const float* __restrict__ bv, float* __restrict__ hout,
    unsigned short* __restrict__ qc){
  int w = threadIdx.x >> 6, lane = threadIdx.x & 63;
  size_t row = (size_t)blockIdx.x * 4 + w;
  f32x4 fv = *(const f32x4*)(ff  + row*DD + lane*4);
  f32x4 hv = *(const f32x4*)(hin + row*DD + lane*4);
  float x[4], s = 0.f, ss = 0.f;
  #pragma unroll
  for (int j = 0; j < 4; ++j){ x[j] = fmaxf(fv[j], 0.f) + hv[j]; s += x[j]; ss += x[j]*x[j]; }
  #pragma unroll
  for (int xm = 1; xm < 64; xm <<= 1){ s += __shfl_xor(s, xm); ss += __shfl_xor(ss, xm); }
  float mu = s * (1.f/256.f);
  float var = ss * (1.f/256.f) - mu*mu;
  float rstd = rsqrtf(var + 1e-5f);
  f32x4 o;
  #pragma unroll
  for (int j = 0; j < 4; ++j){ int c = lane*4 + j; o[j] = (x[j]-mu)*rstd*g[c] + bv[c]; }
  *(f32x4*)(hout + row*DD + lane*4) = o;
  if (WRITEQC){
    unsigned v0 = (unsigned)f2bf(o[0]) | ((unsigned)f2bf(o[1]) << 16);
    unsigned v1 = (unsigned)f2bf(o[2]) | ((unsigned)f2bf(o[3]) << 16);
    uint2 pv; pv.x = v0; pv.y = v1;
    *(uint2*)(qc + row*DF + lane*4) = pv;
  }
}

extern "C" void kernel_launch(void* const* d_in, const int* in_sizes, int n_in,
                              void* d_out, int out_size, void* d_ws, size_t ws_size,
                              hipStream_t stream){
  (void)in_sizes; (void)n_in; (void)out_size; (void)ws_size;
  const float* node  = (const float*)d_in[0];
  const float* inx   = (const float*)d_in[1];
  const int*   adj   = (const int*)d_in[2];
  const float* WQi_w = (const float*)d_in[3];
  const float* WQi_b = (const float*)d_in[4];
  const float* WQ_w  = (const float*)d_in[5];
  const float* WQ_b  = (const float*)d_in[6];
  const float* WK_w  = (const float*)d_in[7];
  const float* WK_b  = (const float*)d_in[8];
  const float* WV_w  = (const float*)d_in[9];
  const float* WV_b  = (const float*)d_in[10];
  const float* WF_w  = (const float*)d_in[11];
  const float* WF_b  = (const float*)d_in[12];
  const float* ln_g  = (const float*)d_in[13];
  const float* ln_b  = (const float*)d_in[14];
  float* hout = (float*)d_out;

  char* wsp = (char*)d_ws;
  auto alloc = [&](size_t n){ char* p = wsp; wsp += (n + 255) & ~(size_t)255; return p; };
  unsigned long long* bits = (unsigned long long*)alloc((size_t)RR*BB*NN*16*8);
  unsigned short* qc    = (unsigned short*)alloc((size_t)MM*DF*2);
  float*          x1    = (float*)alloc((size_t)BB*FF_*4);
  unsigned short* wtall = (unsigned short*)alloc((size_t)NPROJ*DF*2);
  float*          ball  = (float*)alloc((size_t)NPROJ*4);
  unsigned short* wtf   = (unsigned short*)alloc((size_t)DD*512*2);
  unsigned short* POUT  = (unsigned short*)alloc((size_t)MM*NPROJ*2);
  unsigned short* vtall = (unsigned short*)alloc((size_t)RR*BB*DD*NN*2);
  unsigned short* hc    = (unsigned short*)alloc((size_t)MM*512*2);
  float*          ffo   = (float*)alloc((size_t)MM*DD*4);

  pack_adj<<<RR*BB*NN/4, 256, 0, stream>>>(adj, bits);

  for (int l = 0; l < LL; ++l){
    x1_proj<<<BB, FF_, 0, stream>>>(inx, WQi_w + (size_t)l*FF_*FF_, WQi_b + l*FF_, x1);
    qc_x1<<<MM/2, 256, 0, stream>>>(x1, qc);
    if (l == 0) qc_h<<<MM, 256, 0, stream>>>(node, qc);

    wcat<<<NPROJ*DF/256, 256, 0, stream>>>(WQ_w + (size_t)l*DF*DD,
                                           WK_w + (size_t)l*RR*DF*DD,
                                           WV_w + (size_t)l*RR*DF*DD, wtall);
    bcat<<<5, 256, 0, stream>>>(WQ_b + l*DD, WK_b + (size_t)l*RR*DD, WV_b + (size_t)l*RR*DD, ball);
    w_to_bf16T<<<512, 256, 0, stream>>>(WF_w + (size_t)l*512*DD, wtf, 512);

    gemm2<0><<<dim3(128,10), 256, 0, stream>>>(qc, DF, wtall, ball, POUT, NPROJ, DF/32);

    transpose2<<<dim3(16,4,RR*BB), 256, 0, stream>>>(POUT, vtall);

    attn2<<<256, 512, 0, stream>>>(POUT, vtall, bits, hc);

    gemm2<1><<<dim3(128,2), 256, 0, stream>>>(hc, 512, wtf, WF_b + l*DD, ffo, DD, 512/32);

    const float* hsrc = l ? (const float*)hout : node;
    if (l == 0) ln_res2<1><<<MM/4, 256, 0, stream>>>(ffo, hsrc, ln_g, ln_b, hout, qc);
    else        ln_res2<0><<<MM/4, 256, 0, stream>>>(ffo, hsrc, ln_g + DD, ln_b + DD, hout, qc);
  }
}

// Round 3
// 315.850 us; speedup vs baseline: 1.6835x; 1.0899x over previous
//
#include <hip/hip_runtime.h>
#include <hip/hip_bf16.h>

#define BB 16
#define NN 1024
#define DD 256
#define FF_ 128
#define LL 2
#define RR 2
#define DF 384
#define MM (BB*NN)
#define NPROJ 1280
#define PK 768            // POUT row stride (Q:0..255, K0:256..511, K1:512..767)

typedef __attribute__((ext_vector_type(8))) short s16x8;
typedef __attribute__((ext_vector_type(4))) float f32x4;
typedef __attribute__((ext_vector_type(4))) unsigned short us16x4;

__device__ __forceinline__ unsigned short f2bf(float f){
  unsigned u = __builtin_bit_cast(unsigned, f);
  u += 0x7fff + ((u >> 16) & 1);
  return (unsigned short)(u >> 16);
}

__device__ __forceinline__ void gload16(const void* g, void* l){
  __builtin_amdgcn_global_load_lds(
      (const __attribute__((address_space(1))) unsigned int*)g,
      (__attribute__((address_space(3))) unsigned int*)l, 16, 0, 0);
}

#define MFMA16(a,b,c) __builtin_amdgcn_mfma_f32_16x16x32_bf16((a),(b),(c),0,0,0)

// ---------------- adj -> bitmask (R,B,N, 16 x u64) ----------------
__global__ __launch_bounds__(256) void pack_adj(const int* __restrict__ adj,
                                                unsigned long long* __restrict__ bits){
  int w = threadIdx.x >> 6, lane = threadIdx.x & 63;
  size_t row = (size_t)blockIdx.x * 4 + w;
  const int* a = adj + row * NN;
  unsigned long long* brow = bits + row * 16;
  #pragma unroll
  for (int j = 0; j < 16; ++j){
    unsigned long long m = __ballot(a[j*64 + lane] != 0);
    if (lane == 0) brow[j] = m;
  }
}

// ---------------- one-shot prep: weights, biases, x1, hbf ----------------
#define PREP_WT   3840
#define PREP_WTF  1024
#define PREP_BALL 10
#define PREP_X1   16
#define PREP_H    2048
#define PREP_TOT  (PREP_WT+PREP_WTF+PREP_BALL+PREP_X1+PREP_H)

__global__ __launch_bounds__(256) void prep(
    const float* __restrict__ node, const float* __restrict__ inx,
    const float* __restrict__ WQi_w, const float* __restrict__ WQi_b,
    const float* __restrict__ WQ_w, const float* __restrict__ WK_w,
    const float* __restrict__ WV_w, const float* __restrict__ WQ_b,
    const float* __restrict__ WK_b, const float* __restrict__ WV_b,
    const float* __restrict__ WF_w,
    unsigned short* __restrict__ wtall, unsigned short* __restrict__ wtf,
    float* __restrict__ ball, unsigned short* __restrict__ x1bf,
    unsigned short* __restrict__ hbf){
  int bid = blockIdx.x, t = threadIdx.x;
  if (bid < PREP_WT){
    int o = bid*256 + t;                       // < 2*1280*384
    int l = o / (NPROJ*DF); int oo = o - l*(NPROJ*DF);
    int n = oo / DF, k = oo - n*DF;
    const float* WQ = WQ_w + (size_t)l*DF*256;
    const float* WK = WK_w + (size_t)l*RR*DF*256;
    const float* WV = WV_w + (size_t)l*RR*DF*256;
    float v;
    if (n < 256)      v = WQ[(size_t)k*256 + n];
    else if (n < 768) v = WK[(size_t)((n-256)>>8)*(DF*256) + (size_t)k*256 + ((n-256)&255)];
    else              v = WV[(size_t)((n-768)>>8)*(DF*256) + (size_t)k*256 + ((n-768)&255)];
    wtall[o] = f2bf(v);
  } else if (bid < PREP_WT + PREP_WTF){
    int o = (bid - PREP_WT)*256 + t;           // < 2*512*256
    int l = o >> 17; int oo = o & 131071;
    int n = oo >> 9, k = oo & 511;
    wtf[o] = f2bf(WF_w[(size_t)l*512*256 + (size_t)k*256 + n]);
  } else if (bid < PREP_WT + PREP_WTF + PREP_BALL){
    int o = (bid - PREP_WT - PREP_WTF)*256 + t;
    if (o < 2*NPROJ){
      int l = o / NPROJ, n = o - l*NPROJ;
      float v = (n < 256) ? WQ_b[l*256 + n]
              : (n < 768) ? WK_b[(size_t)l*512 + (n-256)]
                          : WV_b[(size_t)l*512 + (n-768)];
      ball[o] = v;
    }
  } else if (bid < PREP_WT + PREP_WTF + PREP_BALL + PREP_X1){
    int o = (bid - PREP_WT - PREP_WTF - PREP_BALL)*256 + t;  // < 4096
    int l = o >> 11, bj = o & 2047;
    int b = bj >> 7, j = bj & 127;
    const float* w = WQi_w + (size_t)l*FF_*FF_;
    float s = WQi_b[l*FF_ + j];
    for (int i = 0; i < FF_; ++i) s += inx[b*FF_ + i] * w[i*FF_ + j];
    x1bf[o] = f2bf(s);
  } else {
    int o = (bid - (PREP_TOT - PREP_H))*256 + t;             // < 524288, 8 elems each
    const float4* src = (const float4*)node + (size_t)o*2;
    float4 a = src[0], c = src[1];
    uint4 pk;
    pk.x = (unsigned)f2bf(a.x) | ((unsigned)f2bf(a.y) << 16);
    pk.y = (unsigned)f2bf(a.z) | ((unsigned)f2bf(a.w) << 16);
    pk.z = (unsigned)f2bf(c.x) | ((unsigned)f2bf(c.y) << 16);
    pk.w = (unsigned)f2bf(c.z) | ((unsigned)f2bf(c.w) << 16);
    *(uint4*)(hbf + (size_t)o*8) = pk;
  }
}

// ------------- big projection GEMM: A=concat(hbf,x1), N=1280, K=384 -------------
// bn<6: POUT row-major (stride 768). bn>=6: V written transposed to vtall.
__global__ __launch_bounds__(256) void gemm_big(const unsigned short* __restrict__ hbf,
    const unsigned short* __restrict__ x1l, const unsigned short* __restrict__ Wt,
    const float* __restrict__ bias, unsigned short* __restrict__ POUT,
    unsigned short* __restrict__ vtall){
  __shared__ unsigned short As[2][128*32];
  __shared__ unsigned short Bs[2][128*32];
  int t = threadIdx.x, lane = t & 63, w = t >> 6;
  int wr = w >> 1, wc = w & 1, l15 = lane & 15, lhi = lane >> 4;
  int bm = blockIdx.x, bn = blockIdx.y, bb = bm >> 3;
  f32x4 acc[4][4];
  #pragma unroll
  for (int m = 0; m < 4; ++m)
    #pragma unroll
    for (int n = 0; n < 4; ++n) acc[m][n] = (f32x4){0.f,0.f,0.f,0.f};

  auto STAGE = [&](int bi, int kk){
    #pragma unroll
    for (int i = 0; i < 2; ++i){
      int base = w*2048 + i*1024;
      int off = base + lane*16;
      int row = off >> 6, cb = off & 63;
      const char* asrc = (kk < 8)
        ? (const char*)hbf + ((size_t)(bm*128 + row)*256 + kk*32)*2 + cb
        : (const char*)x1l + ((size_t)bb*128 + (kk-8)*32)*2 + cb;
      gload16(asrc, (char*)As[bi] + base);
      gload16((const char*)Wt + ((size_t)(bn*128 + row)*DF + kk*32)*2 + cb,
              (char*)Bs[bi] + base);
    }
  };

  STAGE(0, 0);
  __syncthreads();
  for (int kk = 0; kk < 12; ++kk){
    int cur = kk & 1;
    if (kk + 1 < 12) STAGE(cur ^ 1, kk + 1);
    s16x8 af[4], bfr[4];
    #pragma unroll
    for (int m = 0; m < 4; ++m) af[m]  = *(const s16x8*)&As[cur][(wr*64 + m*16 + l15)*32 + lhi*8];
    #pragma unroll
    for (int n = 0; n < 4; ++n) bfr[n] = *(const s16x8*)&Bs[cur][(wc*64 + n*16 + l15)*32 + lhi*8];
    __builtin_amdgcn_s_setprio(1);
    #pragma unroll
    for (int m = 0; m < 4; ++m)
      #pragma unroll
      for (int n = 0; n < 4; ++n)
        acc[m][n] = MFMA16(af[m], bfr[n], acc[m][n]);
    __builtin_amdgcn_s_setprio(0);
    __syncthreads();
  }

  if (bn < 6){
    #pragma unroll
    for (int n = 0; n < 4; ++n){
      int gn = bn*128 + wc*64 + n*16 + l15;
      float bv = bias[gn];
      #pragma unroll
      for (int m = 0; m < 4; ++m){
        int gm = bm*128 + wr*64 + m*16 + lhi*4;
        #pragma unroll
        for (int i = 0; i < 4; ++i)
          POUT[(size_t)(gm + i)*PK + gn] = f2bf(acc[m][n][i] + bv);
      }
    }
  } else {
    #pragma unroll
    for (int n = 0; n < 4; ++n){
      int gn = bn*128 + wc*64 + n*16 + l15;
      float bv = bias[gn];
      int rv = gn - 768;
      int r = rv >> 8, d = rv & 255;
      #pragma unroll
      for (int m = 0; m < 4; ++m){
        int mb = (bm & 7)*128 + wr*64 + m*16 + lhi*4;
        us16x4 pk;
        #pragma unroll
        for (int i = 0; i < 4; ++i) pk[i] = f2bf(acc[m][n][i] + bv);
        *(us16x4*)(vtall + ((size_t)((r*16 + bb)*256 + d))*NN + mb) = pk;
      }
    }
  }
}

// ------------- flash attention, dbuf K/V, 8 waves / 128 q-rows -------------
__global__ __launch_bounds__(512, 2) void attn2(const unsigned short* __restrict__ P,
    const unsigned short* __restrict__ VT, const unsigned long long* __restrict__ bits,
    unsigned short* __restrict__ hc){
  __shared__ unsigned short Kt[2][64*256];
  __shared__ unsigned short Vt[2][256*64];
  __shared__ unsigned short Pl[8][16*68];
  int t = threadIdx.x, lane = t & 63, w = t >> 6, l15 = lane & 15, lhi = lane >> 4;
  int F = blockIdx.x;
  int xcd = F & 7, j = F >> 3;
  int qt = j & 7;
  int gidx = xcd*4 + (j >> 3);
  int b = gidx & 15, r = gidx >> 4;
  const float C = 0.09016844f;           // (1/16) * log2(e)

  size_t kcol = 256 + (size_t)r*256;
  const unsigned short* Vb = VT + ((size_t)(r*16 + b))*256*NN;

  s16x8 qf[8];
  {
    int qrow = qt*128 + w*16 + l15;
    const unsigned short* qp = P + ((size_t)(b*NN + qrow))*PK + lhi*8;
    #pragma unroll
    for (int dc = 0; dc < 8; ++dc) qf[dc] = *(const s16x8*)(qp + dc*32);
  }

  f32x4 acc[16];
  #pragma unroll
  for (int i = 0; i < 16; ++i) acc[i] = (f32x4){0.f,0.f,0.f,0.f};
  float mrow[4] = {-3e38f,-3e38f,-3e38f,-3e38f};
  float lrow[4] = {0.f,0.f,0.f,0.f};
  size_t bitrow = ((size_t)(r*BB + b))*NN + qt*128 + w*16 + lhi*4;

  auto STAGE = [&](int bi, int kt){
    #pragma unroll
    for (int i = 0; i < 4; ++i){
      int base = w*4096 + i*1024;
      int off = base + lane*16;
      int row = off >> 9, cb = off & 511;
      int scb = cb ^ ((row & 7) << 4);
      gload16((const char*)P + ((size_t)(b*NN + kt*64 + row)*PK + kcol)*2 + scb,
              (char*)Kt[bi] + base);
    }
    #pragma unroll
    for (int i = 0; i < 4; ++i){
      int base = w*4096 + i*1024;
      int off = base + lane*16;
      int row = off >> 7, cb = off & 127;
      int scb = cb ^ ((row & 7) << 4);
      gload16((const char*)Vb + ((size_t)row*NN + kt*64)*2 + scb,
              (char*)Vt[bi] + base);
    }
  };

  STAGE(0, 0);
  __syncthreads();

  for (int kt = 0; kt < 16; ++kt){
    int cur = kt & 1;
    if (kt + 1 < 16) STAGE(cur ^ 1, kt + 1);

    // S = Q K^T
    f32x4 sf[4];
    #pragma unroll
    for (int ks = 0; ks < 4; ++ks){
      sf[ks] = (f32x4){0.f,0.f,0.f,0.f};
      int krow = ks*16 + l15;
      __builtin_amdgcn_s_setprio(1);
      #pragma unroll
      for (int dc = 0; dc < 8; ++dc){
        int bo = krow*512 + (((dc*32 + lhi*8)*2) ^ ((krow & 7) << 4));
        s16x8 kf = *(const s16x8*)((const char*)Kt[cur] + bo);
        sf[ks] = MFMA16(qf[dc], kf, sf[ks]);
      }
      __builtin_amdgcn_s_setprio(0);
    }

    // mask + online softmax (exp2 domain, defer-max)
    unsigned short* pw = &Pl[w][0];
    #pragma unroll
    for (int i = 0; i < 4; ++i){
      unsigned long long mwv = bits[(bitrow + i)*16 + kt];
      float sv[4]; float tm = -3e38f;
      #pragma unroll
      for (int ks = 0; ks < 4; ++ks){
        float s = sf[ks][i] * C;
        bool on = (mwv >> (ks*16 + l15)) & 1ULL;
        s = on ? s : -1.443e9f;
        sv[ks] = s;
        tm = fmaxf(tm, s);
      }
      #pragma unroll
      for (int xm = 1; xm < 16; xm <<= 1) tm = fmaxf(tm, __shfl_xor(tm, xm));
      float mn = mrow[i];
      if (tm > mn + 11.6f){
        float f = exp2f(mn - tm);
        mrow[i] = tm; mn = tm;
        lrow[i] *= f;
        #pragma unroll
        for (int dt = 0; dt < 16; ++dt) acc[dt][i] *= f;
      }
      float rs = 0.f;
      #pragma unroll
      for (int ks = 0; ks < 4; ++ks){
        float e = exp2f(sv[ks] - mn);
        pw[(lhi*4 + i)*68 + ks*16 + l15] = f2bf(e);
        rs += e;
      }
      #pragma unroll
      for (int xm = 1; xm < 16; xm <<= 1) rs += __shfl_xor(rs, xm);
      lrow[i] += rs;
    }

    s16x8 pa[2];
    #pragma unroll
    for (int kc = 0; kc < 2; ++kc)
      pa[kc] = *(const s16x8*)&pw[l15*68 + kc*32 + lhi*8];

    // PV
    __builtin_amdgcn_s_setprio(1);
    #pragma unroll
    for (int dt = 0; dt < 16; ++dt){
      int vrow = dt*16 + l15;
      #pragma unroll
      for (int kc = 0; kc < 2; ++kc){
        int bo = vrow*128 + (((kc*32 + lhi*8)*2) ^ ((vrow & 7) << 4));
        s16x8 vf = *(const s16x8*)((const char*)Vt[cur] + bo);
        acc[dt] = MFMA16(pa[kc], vf, acc[dt]);
      }
    }
    __builtin_amdgcn_s_setprio(0);

    __syncthreads();   // drains vmcnt(0): next buffer landed, cur free for overwrite
  }

  #pragma unroll
  for (int i = 0; i < 4; ++i){
    float inv = 1.f / lrow[i];
    int q = qt*128 + w*16 + lhi*4 + i;
    unsigned short* hrow = hc + ((size_t)(b*NN + q))*(RR*DD) + r*DD;
    #pragma unroll
    for (int dt = 0; dt < 16; ++dt)
      hrow[dt*16 + l15] = f2bf(acc[dt][i] * inv);
  }
}

// ------------- FF GEMM: A=hc (K=512), out f32 (stride 256) -------------
__global__ __launch_bounds__(256) void gemm_ff(const unsigned short* __restrict__ A,
    const unsigned short* __restrict__ Wt, const float* __restrict__ bias,
    float* __restrict__ out){
  __shared__ unsigned short As[2][128*32];
  __shared__ unsigned short Bs[2][128*32];
  int t = threadIdx.x, lane = t & 63, w = t >> 6;
  int wr = w >> 1, wc = w & 1, l15 = lane & 15, lhi = lane >> 4;
  int bm = blockIdx.x, bn = blockIdx.y;
  f32x4 acc[4][4];
  #pragma unroll
  for (int m = 0; m < 4; ++m)
    #pragma unroll
    for (int n = 0; n < 4; ++n) acc[m][n] = (f32x4){0.f,0.f,0.f,0.f};

  auto STAGE = [&](int bi, int kk){
    #pragma unroll
    for (int i = 0; i < 2; ++i){
      int base = w*2048 + i*1024;
      int off = base + lane*16;
      int row = off >> 6, cb = off & 63;
      gload16((const char*)A  + ((size_t)(bm*128 + row)*512 + kk*32)*2 + cb,
              (char*)As[bi] + base);
      gload16((const char*)Wt + ((size_t)(bn*128 + row)*512 + kk*32)*2 + cb,
              (char*)Bs[bi] + base);
    }
  };

  STAGE(0, 0);
  __syncthreads();
  for (int kk = 0; kk < 16; ++kk){
    int cur = kk & 1;
    if (kk + 1 < 16) STAGE(cur ^ 1, kk + 1);
    s16x8 af[4], bfr[4];
    #pragma unroll
    for (int m = 0; m < 4; ++m) af[m]  = *(const s16x8*)&As[cur][(wr*64 + m*16 + l15)*32 + lhi*8];
    #pragma unroll
    for (int n = 0; n < 4; ++n) bfr[n] = *(const s16x8*)&Bs[cur][(wc*64 + n*16 + l15)*32 + lhi*8];
    __builtin_amdgcn_s_setprio(1);
    #pragma unroll
    for (int m = 0; m < 4; ++m)
      #pragma unroll
      for (int n = 0; n < 4; ++n)
        acc[m][n] = MFMA16(af[m], bfr[n], acc[m][n]);
    __builtin_amdgcn_s_setprio(0);
    __syncthreads();
  }

  #pragma unroll
  for (int n = 0; n < 4; ++n){
    int gn = bn*128 + wc*64 + n*16 + l15;
    float bv = bias[gn];
    #pragma unroll
    for (int m = 0; m < 4; ++m){
      int gm = bm*128 + wr*64 + m*16 + lhi*4;
      #pragma unroll
      for (int i = 0; i < 4; ++i)
        out[(size_t)(gm + i)*DD + gn] = acc[m][n][i] + bv;
    }
  }
}

// ------------- relu + residual + layernorm (+ optional hbf write) -------------
template<int WRITEH>
__global__ __launch_bounds__(256) void ln_res2(const float* __restrict__ ff,
    const float* __restrict__ hin, const float* __restrict__ g,
    const float* __restrict__ bv, float* __restrict__ hout,
    unsigned short* __restrict__ hbf){
  int w = threadIdx.x >> 6, lane = threadIdx.x & 63;
  size_t row = (size_t)blockIdx.x * 4 + w;
  f32x4 fv = *(const f32x4*)(ff  + row*DD + lane*4);
  f32x4 hv = *(const f32x4*)(hin + row*DD + lane*4);
  float x[4], s = 0.f, ss = 0.f;
  #pragma unroll
  for (int j = 0; j < 4; ++j){ x[j] = fmaxf(fv[j], 0.f) + hv[j]; s += x[j]; ss += x[j]*x[j]; }
  #pragma unroll
  for (int xm = 1; xm < 64; xm <<= 1){ s += __shfl_xor(s, xm); ss += __shfl_xor(ss, xm); }
  float mu = s * (1.f/256.f);
  float var = ss * (1.f/256.f) - mu*mu;
  float rstd = rsqrtf(var + 1e-5f);
  f32x4 o;
  #pragma unroll
  for (int j = 0; j < 4; ++j){ int c = lane*4 + j; o[j] = (x[j]-mu)*rstd*g[c] + bv[c]; }
  *(f32x4*)(hout + row*DD + lane*4) = o;
  if (WRITEH){
    uint2 pv;
    pv.x = (unsigned)f2bf(o[0]) | ((unsigned)f2bf(o[1]) << 16);
    pv.y = (unsigned)f2bf(o[2]) | ((unsigned)f2bf(o[3]) << 16);
    *(uint2*)(hbf + row*DD + lane*4) = pv;
  }
}

extern "C" void kernel_launch(void* const* d_in, const int* in_sizes, int n_in,
                              void* d_out, int out_size, void* d_ws, size_t ws_size,
                              hipStream_t stream){
  (void)in_sizes; (void)n_in; (void)out_size; (void)ws_size;
  const float* node  = (const float*)d_in[0];
  const float* inx   = (const float*)d_in[1];
  const int*   adj   = (const int*)d_in[2];
  const float* WQi_w = (const float*)d_in[3];
  const float* WQi_b = (const float*)d_in[4];
  const float* WQ_w  = (const float*)d_in[5];
  const float* WQ_b  = (const float*)d_in[6];
  const float* WK_w  = (const float*)d_in[7];
  const float* WK_b  = (const float*)d_in[8];
  const float* WV_w  = (const float*)d_in[9];
  const float* WV_b  = (const float*)d_in[10];
  const float* WF_w  = (const float*)d_in[11];
  const float* WF_b  = (const float*)d_in[12];
  const float* ln_g  = (const float*)d_in[13];
  const float* ln_b  = (const float*)d_in[14];
  float* hout = (float*)d_out;

  char* wsp = (char*)d_ws;
  auto alloc = [&](size_t n){ char* p = wsp; wsp += (n + 255) & ~(size_t)255; return p; };
  unsigned long long* bits = (unsigned long long*)alloc((size_t)RR*BB*NN*16*8);
  unsigned short* wtall = (unsigned short*)alloc((size_t)2*NPROJ*DF*2);
  unsigned short* wtf   = (unsigned short*)alloc((size_t)2*DD*512*2);
  float*          ball  = (float*)alloc((size_t)2*NPROJ*4);
  unsigned short* x1bf  = (unsigned short*)alloc((size_t)2*BB*FF_*2);
  unsigned short* hbf   = (unsigned short*)alloc((size_t)MM*DD*2);
  unsigned short* POUT  = (unsigned short*)alloc((size_t)MM*PK*2);
  unsigned short* vtall = (unsigned short*)alloc((size_t)RR*BB*DD*NN*2);
  unsigned short* hc    = (unsigned short*)alloc((size_t)MM*512*2);
  float*          ffo   = (float*)alloc((size_t)MM*DD*4);

  pack_adj<<<RR*BB*NN/4, 256, 0, stream>>>(adj, bits);
  prep<<<PREP_TOT, 256, 0, stream>>>(node, inx, WQi_w, WQi_b, WQ_w, WK_w, WV_w,
                                     WQ_b, WK_b, WV_b, WF_w,
                                     wtall, wtf, ball, x1bf, hbf);

  for (int l = 0; l < LL; ++l){
    gemm_big<<<dim3(128,10), 256, 0, stream>>>(hbf, x1bf + (size_t)l*BB*FF_,
        wtall + (size_t)l*NPROJ*DF, ball + (size_t)l*NPROJ, POUT, vtall);

    attn2<<<256, 512, 0, stream>>>(POUT, vtall, bits, hc);

    gemm_ff<<<dim3(128,2), 256, 0, stream>>>(hc, wtf + (size_t)l*DD*512, WF_b + l*DD, ffo);

    if (l == 0) ln_res2<1><<<MM/4, 256, 0, stream>>>(ffo, node, ln_g, ln_b, hout, hbf);
    else        ln_res2<0><<<MM/4, 256, 0, stream>>>(ffo, (const float*)hout,
                                                     ln_g + DD, ln_b + DD, hout, nullptr);
  }
}